// Round 8
// baseline (1823.219 us; speedup 1.0000x reference)
//
#include <hip/hip_runtime.h>
#include <hip/hip_bf16.h>

typedef unsigned short u16;
typedef unsigned int u32;
typedef __attribute__((ext_vector_type(8))) short short8;
typedef __attribute__((ext_vector_type(4))) float floatx4;

#define NPIX 12544   // 112*112 = 49 * 256
#define KDIM 768     // channels = 24 * 32
#define EPSF 1e-8f
#define NCH 24       // K chunks of 32
#define NTILE 49     // 12544 / 256

// ---------------------------------------------------------------- async G->LDS
__device__ __forceinline__ void gload_lds16(const void* g, void* l) {
  __builtin_amdgcn_global_load_lds(
      (const __attribute__((address_space(1))) void*)g,
      (__attribute__((address_space(3))) void*)l, 16, 0, 0);
}

// sortable-uint encoding of float (monotone): max over enc == max over float
__device__ __forceinline__ u32 enc_f32(float f) {
  u32 u = __float_as_uint(f);
  return (u & 0x80000000u) ? ~u : (u | 0x80000000u);
}
__device__ __forceinline__ float dec_f32(u32 e) {
  u32 u = (e & 0x80000000u) ? (e & 0x7FFFFFFFu) : ~e;
  return __uint_as_float(u);
}

// ---------------------------------------------------------------- K1: column sum-of-squares partials
// grid (49, 8), block 256. pa/pb: [8][NPIX]
__global__ void colsumsq_kernel(const float* __restrict__ a, const float* __restrict__ b,
                                float* __restrict__ pa, float* __restrict__ pb) {
  int i = blockIdx.x * 256 + threadIdx.x;
  int c0 = blockIdx.y * 96;
  float sa = 0.f, sb = 0.f;
#pragma unroll 4
  for (int c = c0; c < c0 + 96; ++c) {
    float va = a[(size_t)c * NPIX + i];
    float vb = b[(size_t)c * NPIX + i];
    sa += va * va;
    sb += vb * vb;
  }
  pa[(size_t)blockIdx.y * NPIX + i] = sa;
  pb[(size_t)blockIdx.y * NPIX + i] = sb;
}

// ---------------------------------------------------------------- K2: 1/(sqrt(sum+eps)+eps) + zero the atomic-max buffer
// grid 49, block 256
__global__ void rnorm_kernel(const float* __restrict__ pa, const float* __restrict__ pb,
                             float* __restrict__ ra, float* __restrict__ rb,
                             u32* __restrict__ part) {
  int i = blockIdx.x * 256 + threadIdx.x;
  float sa = 0.f, sb = 0.f;
#pragma unroll
  for (int c = 0; c < 8; ++c) {
    sa += pa[(size_t)c * NPIX + i];
    sb += pb[(size_t)c * NPIX + i];
  }
  ra[i] = 1.f / (sqrtf(sa + EPSF) + EPSF);
  rb[i] = 1.f / (sqrtf(sb + EPSF) + EPSF);
  part[i] = 0u;  // encoded floor (< enc of any finite float)
}

// ---------------------------------------------------------------- K3: transpose + normalize + bf16 cast
// (C,N) f32 -> (N,C) bf16.  grid (392, 24, 2), block 256 (=32x8)
__global__ void transpose_kernel(const float* __restrict__ a, const float* __restrict__ b,
                                 const float* __restrict__ ra, const float* __restrict__ rb,
                                 u16* __restrict__ Ar, u16* __restrict__ Br) {
  const float* src = blockIdx.z ? b : a;
  const float* rn  = blockIdx.z ? rb : ra;
  u16* dst         = blockIdx.z ? Br : Ar;
  __shared__ float tile[32][33];
  int i0 = blockIdx.x * 32;
  int c0 = blockIdx.y * 32;
  int tx = threadIdx.x & 31;
  int ty = threadIdx.x >> 5;  // 0..7
#pragma unroll
  for (int d = 0; d < 4; ++d) {
    int c = c0 + ty + d * 8;
    tile[ty + d * 8][tx] = src[(size_t)c * NPIX + i0 + tx];
  }
  __syncthreads();
#pragma unroll
  for (int d = 0; d < 4; ++d) {
    int il = ty + d * 8;
    int gi = i0 + il;
    float v = tile[tx][il] * rn[gi];
    __hip_bfloat16 h = __float2bfloat16(v);
    dst[(size_t)gi * KDIM + c0 + tx] = *reinterpret_cast<u16*>(&h);
  }
}

// ---------------------------------------------------------------- K4: 256x256 tile, 8 waves,
// counted-vmcnt 4-slot ring + WAVE-STAGGERED phase order + setprio (T5), balanced XCDs.
// Round-8 diagnosis: r7 showed SGB (compile-time interleave) is null — the serializer is
// RUNTIME lockstep: both waves of a SIMD are released by the same barrier, both issue
// ds_reads, both then grind MFMA; LDS port and matrix pipe alternate (per-chunk 2750 cyc
// vs ~1500 perfect-overlap floor). Fix: stagger phase ORDER by SIMD-pair parity
// (wave w -> SIMD w&3, so sw=(wid>>2)&1 splits each SIMD's two waves):
//   order A (sw=0): read af2; MFMA1; [vm+bar]; stage; read next; MFMA2
//   order B (sw=1): MFMA1; read af2; [vm+bar]; MFMA2; stage; read next
// After every barrier each SIMD has one wave in MFMA and one issuing LDS ops.
// This creates the wave role-split T5 needs -> restore s_setprio(1) around MFMA clusters
// (dropped in r7; catalog: +21-39% with role-split, 0 without). SGB ladders removed (null).
// Slot-lifetime safety (both orders): every read of slot s is lgkm-drained by a same-wave
// MFMA before that wave's next barrier; stage into slot (c-1)&3 is issued only after
// barrier(c), which all waves reach only after their chunk-(c-1) drains. Order-B's
// end-of-chunk next-frag reads target slot (c+1)&3, never the slot staged next chunk.
// Ring/tail (r5-proven): vmcnt(4) steady (2 chunks in flight), 4/0/none at 21/22/23.
// LDS: 4 ring slots x (256x32 bf16) x {A,B} = 128 KiB, 1 block/CU.
// Swizzle (r5-proven, 0 conflicts): LDS(row r, 16B-slot s) holds k-group (s-(r>>1))&3;
// global source pre-swizzled, LDS dest linear (both-sides-or-neither).
// Dispatch (r7-proven balance): grid (8,301): XCD k owns cols {k,k+8,...,k+40}, rt slow
// chip-synced; col-48 remainder round-robins rows across XCDs. 300/301 blocks per XCD.
__global__ __launch_bounds__(512, 2) void gemm_max_kernel(const u16* __restrict__ Ar,
                                                          const u16* __restrict__ Br,
                                                          u32* __restrict__ part) {
  const int xcd = blockIdx.x;   // linear%8 round-robins XCDs
  const int idx = blockIdx.y;   // 0..300 sequence within XCD
  int ct, rt;
  if (idx < 294) {
    ct = (idx % 6) * 8 + xcd;   // cols {xcd, 8+xcd, ..., 40+xcd} -> B pinned per XCD
    rt = idx / 6;               // rows advance slowly, chip-synchronized
  } else {
    int j = (idx - 294) * 8 + xcd;  // col 48 remainder: rows round-robin XCDs
    if (j >= NTILE) return;         // 7 dead blocks (xcd>0 at idx==300)
    ct = 48; rt = j;
  }
  const int row_base = rt * 256;
  const int col_base = ct * 256;

  __shared__ alignas(16) u16 As[4 * 8192];  // 4 ring slots: [256 rows][4 slots][8 elems]
  __shared__ alignas(16) u16 Bs[4 * 8192];

  const int tid = threadIdx.x;
  const int lane = tid & 63;
  const int wid = tid >> 6;   // 0..7
  const int wm = wid >> 2;    // A half (0..1)
  const int wn = wid & 3;     // B quarter (0..3)
  const int sw = (wid >> 2) & 1;  // stagger parity: waves w and w+4 share SIMD w&3
  const int l15 = lane & 15;
  const int quad = lane >> 4;

  // staging: thread covers rows (tid>>2) and (tid>>2)+128, 16B slot tid&3.
  const int srow = tid >> 2;                       // 0..127
  const int clog = ((tid & 3) - (srow >> 1)) & 3;  // logical 8-elem k-group (pre-swizzled)
  const u16* gAt = Ar + (size_t)(row_base + srow) * KDIM + clog * 8;
  const u16* gBt = Br + (size_t)(col_base + srow) * KDIM + clog * 8;
  u16* lA = &As[tid * 8];
  u16* lB = &Bs[tid * 8];

#define STAGE4(T)                                                              \
  do {                                                                         \
    gload_lds16(gAt + (T) * 32,              lA + (((T) & 3) << 13));          \
    gload_lds16(gAt + (T) * 32 + 128 * KDIM, lA + (((T) & 3) << 13) + 4096);   \
    gload_lds16(gBt + (T) * 32,              lB + (((T) & 3) << 13));          \
    gload_lds16(gBt + (T) * 32 + 128 * KDIM, lB + (((T) & 3) << 13) + 4096);   \
  } while (0)

  // frag element offsets within a slot: row R, k-quad quad -> R*32 + (((R>>1)+quad)&3)*8
  int aoff[8], boff[4];
#pragma unroll
  for (int mm = 0; mm < 8; ++mm) {
    int R = wm * 128 + mm * 16 + l15;
    aoff[mm] = R * 32 + ((((R >> 1) + quad) & 3) << 3);
  }
#pragma unroll
  for (int nf = 0; nf < 4; ++nf) {
    int Cc = wn * 64 + nf * 16 + l15;
    boff[nf] = Cc * 32 + ((((Cc >> 1) + quad) & 3) << 3);
  }

  floatx4 acc[8][4];
#pragma unroll
  for (int m = 0; m < 8; ++m)
#pragma unroll
    for (int n = 0; n < 4; ++n) acc[m][n] = (floatx4){0.f, 0.f, 0.f, 0.f};

  // prologue: stage chunks 0,1,2; wait chunk 0 landed (1,2 stay in flight); prime frags
  STAGE4(0); STAGE4(1); STAGE4(2);
  asm volatile("s_waitcnt vmcnt(8)" ::: "memory");
  __builtin_amdgcn_s_barrier();
  __builtin_amdgcn_sched_barrier(0);

  short8 afc[4], bfc[4];
#pragma unroll
  for (int mm = 0; mm < 4; ++mm) afc[mm] = *(const short8*)&As[aoff[mm]];
#pragma unroll
  for (int nf = 0; nf < 4; ++nf) bfc[nf] = *(const short8*)&Bs[boff[nf]];

#define MFMA_PHI1                                                                             \
  __builtin_amdgcn_s_setprio(1);                                                              \
  _Pragma("unroll") for (int mm = 0; mm < 4; ++mm)                                            \
    _Pragma("unroll") for (int nf = 0; nf < 4; ++nf)                                          \
        acc[mm][nf] = __builtin_amdgcn_mfma_f32_16x16x32_bf16(afc[mm], bfc[nf],               \
                                                              acc[mm][nf], 0, 0, 0);          \
  __builtin_amdgcn_s_setprio(0);

#define MFMA_PHI2                                                                             \
  __builtin_amdgcn_s_setprio(1);                                                              \
  _Pragma("unroll") for (int mm = 0; mm < 4; ++mm)                                            \
    _Pragma("unroll") for (int nf = 0; nf < 4; ++nf)                                          \
        acc[mm + 4][nf] = __builtin_amdgcn_mfma_f32_16x16x32_bf16(af2[mm], bfc[nf],           \
                                                                  acc[mm + 4][nf], 0, 0, 0);  \
  __builtin_amdgcn_s_setprio(0);

#define READ_AF2                                                                              \
  _Pragma("unroll") for (int mm = 0; mm < 4; ++mm)                                            \
      af2[mm] = *(const short8*)&pAs[aoff[mm + 4]];

#define READ_NEXT                                                                             \
  _Pragma("unroll") for (int mm = 0; mm < 4; ++mm)                                            \
      afn[mm] = *(const short8*)&pAn[aoff[mm]];                                               \
  _Pragma("unroll") for (int nf = 0; nf < 4; ++nf)                                            \
      bfn[nf] = *(const short8*)&pBn[boff[nf]];

#define WAITBAR(VMSTR)                                                                        \
  asm volatile("s_waitcnt " VMSTR ::: "memory");                                              \
  __builtin_amdgcn_s_barrier();                                                               \
  __builtin_amdgcn_sched_barrier(0);

#define CHUNK(C, DOSTG, VMSTR, DOWAIT, DONEXT)                                                \
  do {                                                                                        \
    const u16* pAs = &As[((C) & 3) << 13];                                                    \
    const u16* pBs = &Bs[((C) & 3) << 13];                                                    \
    const u16* pAn = &As[(((C) + 1) & 3) << 13];                                              \
    const u16* pBn = &Bs[(((C) + 1) & 3) << 13];                                              \
    (void)pBs;                                                                                \
    short8 af2[4], afn[4], bfn[4];                                                            \
    if (sw == 0) {                                                                            \
      /* order A: reads lead, MFMAs trail */                                                  \
      READ_AF2                                                                                \
      MFMA_PHI1                                                                               \
      if (DOWAIT) { WAITBAR(VMSTR) }                                                          \
      if (DOSTG) STAGE4((C) + 3);                                                             \
      if (DONEXT) { READ_NEXT }                                                               \
      MFMA_PHI2                                                                               \
    } else {                                                                                  \
      /* order B: MFMAs lead, reads trail -> anti-phase with order A on same SIMD */          \
      MFMA_PHI1                                                                               \
      READ_AF2                                                                                \
      if (DOWAIT) { WAITBAR(VMSTR) }                                                          \
      MFMA_PHI2                                                                               \
      if (DOSTG) STAGE4((C) + 3);                                                             \
      if (DONEXT) { READ_NEXT }                                                               \
    }                                                                                         \
    if (DONEXT) {                                                                             \
      _Pragma("unroll") for (int mm = 0; mm < 4; ++mm) afc[mm] = afn[mm];                     \
      _Pragma("unroll") for (int nf = 0; nf < 4; ++nf) bfc[nf] = bfn[nf];                     \
    }                                                                                         \
  } while (0)

  CHUNK(0,  1, "vmcnt(4)", 1, 1);  CHUNK(1,  1, "vmcnt(4)", 1, 1);
  CHUNK(2,  1, "vmcnt(4)", 1, 1);  CHUNK(3,  1, "vmcnt(4)", 1, 1);
  CHUNK(4,  1, "vmcnt(4)", 1, 1);  CHUNK(5,  1, "vmcnt(4)", 1, 1);
  CHUNK(6,  1, "vmcnt(4)", 1, 1);  CHUNK(7,  1, "vmcnt(4)", 1, 1);
  CHUNK(8,  1, "vmcnt(4)", 1, 1);  CHUNK(9,  1, "vmcnt(4)", 1, 1);
  CHUNK(10, 1, "vmcnt(4)", 1, 1);  CHUNK(11, 1, "vmcnt(4)", 1, 1);
  CHUNK(12, 1, "vmcnt(4)", 1, 1);  CHUNK(13, 1, "vmcnt(4)", 1, 1);
  CHUNK(14, 1, "vmcnt(4)", 1, 1);  CHUNK(15, 1, "vmcnt(4)", 1, 1);
  CHUNK(16, 1, "vmcnt(4)", 1, 1);  CHUNK(17, 1, "vmcnt(4)", 1, 1);
  CHUNK(18, 1, "vmcnt(4)", 1, 1);  CHUNK(19, 1, "vmcnt(4)", 1, 1);
  CHUNK(20, 1, "vmcnt(4)", 1, 1);
  CHUNK(21, 0, "vmcnt(4)", 1, 1);
  CHUNK(22, 0, "vmcnt(0)", 1, 1);
  CHUNK(23, 0, "vmcnt(0)", 0, 0);

#undef CHUNK
#undef STAGE4
#undef MFMA_PHI1
#undef MFMA_PHI2
#undef READ_AF2
#undef READ_NEXT
#undef WAITBAR

  // epilogue: per-row max over the 256-col tile.
  // C frag layout: col = l15 (+n*16), row = quad*4 + rr (+m*16, +wm*128)
  // s_max overlays As slot 0: last slot-0 reads (chunk 20) are lgkm-drained by each wave's
  // own chunk-20/21 MFMAs before barrier(22); every wave passes barrier(22) before any
  // epilogue write. Slot-3 reads in chunk 23 don't touch slot 0.
  float* s_max = reinterpret_cast<float*>(&As[0]);
#pragma unroll
  for (int m = 0; m < 8; ++m) {
#pragma unroll
    for (int rr = 0; rr < 4; ++rr) {
      float best = fmaxf(fmaxf(acc[m][0][rr], acc[m][1][rr]),
                         fmaxf(acc[m][2][rr], acc[m][3][rr]));
      best = fmaxf(best, __shfl_xor(best, 1));
      best = fmaxf(best, __shfl_xor(best, 2));
      best = fmaxf(best, __shfl_xor(best, 4));
      best = fmaxf(best, __shfl_xor(best, 8));
      if (l15 == 0)
        s_max[wn * 256 + wm * 128 + m * 16 + quad * 4 + rr] = best;  // unique writer per entry
    }
  }
  __syncthreads();
  if (tid < 256) {
    float mx = fmaxf(fmaxf(s_max[tid], s_max[256 + tid]),
                     fmaxf(s_max[512 + tid], s_max[768 + tid]));
    atomicMax(&part[row_base + tid], enc_f32(mx));
  }
}

// ---------------------------------------------------------------- K5: decode + loss
// single block, 1024 threads; output fp32 scalar
__global__ void finish_kernel(const u32* __restrict__ part, float* __restrict__ out) {
  float v = 0.f;
  for (int i = threadIdx.x; i < NPIX; i += 1024) {
    v += 1.0f - dec_f32(part[i]);
  }
#pragma unroll
  for (int off = 32; off > 0; off >>= 1) v += __shfl_down(v, off);
  __shared__ float red[16];
  int w = threadIdx.x >> 6;
  if ((threadIdx.x & 63) == 0) red[w] = v;
  __syncthreads();
  if (threadIdx.x == 0) {
    float s = 0.f;
#pragma unroll
    for (int k = 0; k < 16; ++k) s += red[k];
    out[0] = s * (1.0f / (float)NPIX);
  }
}

// ---------------------------------------------------------------- launcher
extern "C" void kernel_launch(void* const* d_in, const int* in_sizes, int n_in,
                              void* d_out, int out_size, void* d_ws, size_t ws_size,
                              hipStream_t stream) {
  const float* x = (const float*)d_in[0];
  const float* s = (const float*)d_in[1];
  char* ws = (char*)d_ws;
  // layout (bytes):
  float* pa   = (float*)(ws + 0);         //   401408
  float* pb   = (float*)(ws + 401408);    //   401408
  float* ra   = (float*)(ws + 802816);    //    50176
  float* rb   = (float*)(ws + 852992);    //    50176
  u32*   part = (u32*)  (ws + 903168);    //    50176 (encoded row maxima)
  u16*   Ar   = (u16*)  (ws + 953344);    // 19267584
  u16*   Br   = (u16*)  (ws + 20220928);  // 19267584  -> total 39488512 B

  colsumsq_kernel<<<dim3(49, 8), 256, 0, stream>>>(x, s, pa, pb);
  rnorm_kernel<<<49, 256, 0, stream>>>(pa, pb, ra, rb, part);
  transpose_kernel<<<dim3(392, 24, 2), 256, 0, stream>>>(x, s, ra, rb, Ar, Br);
  gemm_max_kernel<<<dim3(8, 301), 512, 0, stream>>>(Ar, Br, part);
  finish_kernel<<<1, 1024, 0, stream>>>(part, (float*)d_out);
}

// Round 10
// 410.256 us; speedup vs baseline: 4.4441x; 4.4441x over previous
//
#include <hip/hip_runtime.h>
#include <hip/hip_bf16.h>

typedef unsigned short u16;
typedef unsigned int u32;
typedef __attribute__((ext_vector_type(8))) short short8;
typedef __attribute__((ext_vector_type(4))) float floatx4;

#define NPIX 12544   // 112*112 = 49 * 256
#define KDIM 768     // channels = 12 * 64
#define EPSF 1e-8f
#define NT 12        // K tiles of 64
#define NTILE 49     // 12544 / 256

// ---------------------------------------------------------------- async G->LDS
__device__ __forceinline__ void gload_lds16(const void* g, void* l) {
  __builtin_amdgcn_global_load_lds(
      (const __attribute__((address_space(1))) void*)g,
      (__attribute__((address_space(3))) void*)l, 16, 0, 0);
}

// sortable-uint encoding of float (monotone): max over enc == max over float
__device__ __forceinline__ u32 enc_f32(float f) {
  u32 u = __float_as_uint(f);
  return (u & 0x80000000u) ? ~u : (u | 0x80000000u);
}
__device__ __forceinline__ float dec_f32(u32 e) {
  u32 u = (e & 0x80000000u) ? (e & 0x7FFFFFFFu) : ~e;
  return __uint_as_float(u);
}

// ---------------------------------------------------------------- K1: column sum-of-squares partials
// grid (49, 8), block 256. pa/pb: [8][NPIX]
__global__ void colsumsq_kernel(const float* __restrict__ a, const float* __restrict__ b,
                                float* __restrict__ pa, float* __restrict__ pb) {
  int i = blockIdx.x * 256 + threadIdx.x;
  int c0 = blockIdx.y * 96;
  float sa = 0.f, sb = 0.f;
#pragma unroll 4
  for (int c = c0; c < c0 + 96; ++c) {
    float va = a[(size_t)c * NPIX + i];
    float vb = b[(size_t)c * NPIX + i];
    sa += va * va;
    sb += vb * vb;
  }
  pa[(size_t)blockIdx.y * NPIX + i] = sa;
  pb[(size_t)blockIdx.y * NPIX + i] = sb;
}

// ---------------------------------------------------------------- K2: 1/(sqrt(sum+eps)+eps) + zero the atomic-max buffer
// grid 49, block 256
__global__ void rnorm_kernel(const float* __restrict__ pa, const float* __restrict__ pb,
                             float* __restrict__ ra, float* __restrict__ rb,
                             u32* __restrict__ part) {
  int i = blockIdx.x * 256 + threadIdx.x;
  float sa = 0.f, sb = 0.f;
#pragma unroll
  for (int c = 0; c < 8; ++c) {
    sa += pa[(size_t)c * NPIX + i];
    sb += pb[(size_t)c * NPIX + i];
  }
  ra[i] = 1.f / (sqrtf(sa + EPSF) + EPSF);
  rb[i] = 1.f / (sqrtf(sb + EPSF) + EPSF);
  part[i] = 0u;  // encoded floor (< enc of any finite float)
}

// ---------------------------------------------------------------- K3: transpose + normalize + bf16 cast
// (C,N) f32 -> (N,C) bf16.  grid (392, 24, 2), block 256 (=32x8)
__global__ void transpose_kernel(const float* __restrict__ a, const float* __restrict__ b,
                                 const float* __restrict__ ra, const float* __restrict__ rb,
                                 u16* __restrict__ Ar, u16* __restrict__ Br) {
  const float* src = blockIdx.z ? b : a;
  const float* rn  = blockIdx.z ? rb : ra;
  u16* dst         = blockIdx.z ? Br : Ar;
  __shared__ float tile[32][33];
  int i0 = blockIdx.x * 32;
  int c0 = blockIdx.y * 32;
  int tx = threadIdx.x & 31;
  int ty = threadIdx.x >> 5;  // 0..7
#pragma unroll
  for (int d = 0; d < 4; ++d) {
    int c = c0 + ty + d * 8;
    tile[ty + d * 8][tx] = src[(size_t)c * NPIX + i0 + tx];
  }
  __syncthreads();
#pragma unroll
  for (int d = 0; d < 4; ++d) {
    int il = ty + d * 8;
    int gi = i0 + il;
    float v = tile[tx][il] * rn[gi];
    __hip_bfloat16 h = __float2bfloat16(v);
    dst[(size_t)gi * KDIM + c0 + tx] = *reinterpret_cast<u16*>(&h);
  }
}

// ---------------------------------------------------------------- K4: 256x256 tile, 8 waves, BK=64,
// m201-style 4-phase schedule + per-phase HALF-TILE staging + 2-tile-deep COUNTED vmcnt.
// Round-10 fix of r9's NaN: r9 changed the staging dest to doff = (tid>>2)*64 + (tid&3)*8,
// which is NOT lane-linear — global_load_lds writes wave-uniform base + lane*16B (rule #21,
// m104), so lanes >=4 landed in wrong slots -> garbage frags. Restored r3's VERIFIED
// geometry: srow = tid>>3 (0..63), phys slot = tid&7, clog = ((tid&7)-srow)&7 (pre-swizzled
// source), dests tid*8 and 4096+tid*8 — both lane-linear (consecutive lanes -> consecutive
// 16B), same 2 gloads/thread so the r9 vmcnt ledger is unchanged.
// Schedule per tile t (buf=t&1; each phase: reads+stage -> bar -> lgkmcnt(0) -> setprio(1)
// -> 16 MFMA -> setprio(0) -> bar):
//   P1: read A(m0-3,k0)+B(n,k0) [8]; stage B1(t+1)->bufn  [freed at t-1 P3 bar]
//   P2: read A(m4-7,k0) [4];         stage A0(t+1)->bufn  [freed at t-1 P4 bar]
//   P3: read A(m0-3,k1)+B(n,k1) [8]; stage A1(t+1)->bufn  [freed at t-1 P4 bar]
//   P4: read A(m4-7,k1) [4];         stage B0(t+2)->buf   [freed at THIS tile's P3 bar:
//       all waves lgkm-drained B-k1 reads before it]; after MFMA: vmcnt(2) (t<=9: tile t+1
//       landed, B0(t+2) in flight) / vmcnt(0) (t==10) / none (t==11). Never 0 mid-loop.
// Prologue: {B0,B1,A0,A1}(0) + B0(1) = 10 loads, vmcnt(2), barrier.
// LDS: As/Bs[2 buf][2 half][128x64 bf16] = 128 KiB, 1 block/CU.
// Swizzle (r3/r5-proven, 0 conflicts): LDS(row r, phys 16B-slot s) holds logical k-slot
// (s-r)&7; read phys slot = (kk*4+quad+row)&7.
// Dispatch (r7-proven balance): grid (8,301): XCD k owns cols {k,k+8,...,k+40}, rt slow
// chip-synced; col-48 remainder round-robins rows across XCDs. 300/301 blocks per XCD.
__global__ __launch_bounds__(512, 2) void gemm_max_kernel(const u16* __restrict__ Ar,
                                                          const u16* __restrict__ Br,
                                                          u32* __restrict__ part) {
  const int xcd = blockIdx.x;   // linear%8 round-robins XCDs
  const int idx = blockIdx.y;   // 0..300 sequence within XCD
  int ct, rt;
  if (idx < 294) {
    ct = (idx % 6) * 8 + xcd;   // cols {xcd, 8+xcd, ..., 40+xcd} -> B pinned per XCD
    rt = idx / 6;               // rows advance slowly, chip-synchronized
  } else {
    int j = (idx - 294) * 8 + xcd;  // col 48 remainder: rows round-robin XCDs
    if (j >= NTILE) return;         // 7 dead blocks (xcd>0 at idx==300)
    ct = 48; rt = j;
  }
  const int row_base = rt * 256;
  const int col_base = ct * 256;

  __shared__ alignas(16) u16 As[2][2][128 * 64];  // [buf][half][row*64 + physslot*8]
  __shared__ alignas(16) u16 Bs[2][2][128 * 64];

  const int tid = threadIdx.x;
  const int lane = tid & 63;
  const int wid = tid >> 6;   // 0..7
  const int wm = wid >> 2;    // A half (0..1)
  const int wn = wid & 3;     // B quarter (0..3)
  const int l15 = lane & 15;
  const int quad = lane >> 4;
  const int rb0 = (wn & 1) * 64;  // B row base within half (wn>>1)

  // staging (r3-verified, lane-linear dest): thread covers rows srow and srow+64 of the
  // 128-row half-tile, phys slot tid&7. logical k-slot = (phys - row)&7 -> pre-swizzled
  // source (row+64 same: 64%8==0). Dest tid*8 / 4096+tid*8: consecutive lanes ->
  // consecutive 16B, matching global_load_lds's uniform-base + lane*16B write (rule #21).
  const int srow = tid >> 3;                      // 0..63
  const int clog = ((tid & 7) - srow) & 7;        // logical k-slot for phys slot tid&7
  const u16* gA = Ar + (size_t)(row_base + srow) * KDIM + clog * 8;
  const u16* gB = Br + (size_t)(col_base + srow) * KDIM + clog * 8;

#define SH_A(b, h, t)                                                          \
  do {                                                                         \
    const u16* g = gA + (size_t)(h) * 128 * KDIM + (t) * 64;                   \
    gload_lds16(g, &As[b][h][tid * 8]);                                        \
    gload_lds16(g + (size_t)64 * KDIM, &As[b][h][4096 + tid * 8]);             \
  } while (0)
#define SH_B(b, h, t)                                                          \
  do {                                                                         \
    const u16* g = gB + (size_t)(h) * 128 * KDIM + (t) * 64;                   \
    gload_lds16(g, &Bs[b][h][tid * 8]);                                        \
    gload_lds16(g + (size_t)64 * KDIM, &Bs[b][h][4096 + tid * 8]);             \
  } while (0)

  // frag read address (elements): row-major 64/row, phys slot rotated by row
  auto swz = [&](int row, int kk) {
    return row * 64 + ((((kk << 2) + quad + row) & 7) << 3);
  };

  floatx4 acc[8][4];
#pragma unroll
  for (int m = 0; m < 8; ++m)
#pragma unroll
    for (int n = 0; n < 4; ++n) acc[m][n] = (floatx4){0.f, 0.f, 0.f, 0.f};

  // prologue: tile 0 complete + B0(1); vmcnt(2) keeps B0(1) in flight
  SH_B(0, 0, 0); SH_B(0, 1, 0); SH_A(0, 0, 0); SH_A(0, 1, 0);
  SH_B(1, 0, 1);
  asm volatile("s_waitcnt vmcnt(2)" ::: "memory");
  __builtin_amdgcn_s_barrier();

#define BARMFMA_HEAD                                                           \
  __builtin_amdgcn_s_barrier();                                                \
  asm volatile("s_waitcnt lgkmcnt(0)" ::: "memory");                           \
  __builtin_amdgcn_sched_barrier(0);                                           \
  __builtin_amdgcn_s_setprio(1);

  for (int t = 0; t < NT; ++t) {
    const int buf = t & 1;
    const int bufn = buf ^ 1;
    const u16* pA = &As[buf][wm][0];
    const u16* pB = &Bs[buf][wn >> 1][0];
    const bool s1 = (t + 1 < NT);
    const bool s2 = (t + 2 < NT);
    short8 af[4], bf[4];

    // ---------------- P1: k0, m0-3 x n0-3
#pragma unroll
    for (int mm = 0; mm < 4; ++mm) af[mm] = *(const short8*)&pA[swz(mm * 16 + l15, 0)];
#pragma unroll
    for (int nf = 0; nf < 4; ++nf) bf[nf] = *(const short8*)&pB[swz(rb0 + nf * 16 + l15, 0)];
    if (s1) SH_B(bufn, 1, t + 1);
    BARMFMA_HEAD
#pragma unroll
    for (int mm = 0; mm < 4; ++mm)
#pragma unroll
      for (int nf = 0; nf < 4; ++nf)
        acc[mm][nf] = __builtin_amdgcn_mfma_f32_16x16x32_bf16(af[mm], bf[nf], acc[mm][nf], 0, 0, 0);
    __builtin_amdgcn_s_setprio(0);
    __builtin_amdgcn_s_barrier();

    // ---------------- P2: k0, m4-7 x n0-3 (bf reused)
#pragma unroll
    for (int mm = 0; mm < 4; ++mm) af[mm] = *(const short8*)&pA[swz((mm + 4) * 16 + l15, 0)];
    if (s1) SH_A(bufn, 0, t + 1);
    BARMFMA_HEAD
#pragma unroll
    for (int mm = 0; mm < 4; ++mm)
#pragma unroll
      for (int nf = 0; nf < 4; ++nf)
        acc[mm + 4][nf] = __builtin_amdgcn_mfma_f32_16x16x32_bf16(af[mm], bf[nf], acc[mm + 4][nf], 0, 0, 0);
    __builtin_amdgcn_s_setprio(0);
    __builtin_amdgcn_s_barrier();

    // ---------------- P3: k1, m0-3 x n0-3
#pragma unroll
    for (int mm = 0; mm < 4; ++mm) af[mm] = *(const short8*)&pA[swz(mm * 16 + l15, 1)];
#pragma unroll
    for (int nf = 0; nf < 4; ++nf) bf[nf] = *(const short8*)&pB[swz(rb0 + nf * 16 + l15, 1)];
    if (s1) SH_A(bufn, 1, t + 1);
    BARMFMA_HEAD
#pragma unroll
    for (int mm = 0; mm < 4; ++mm)
#pragma unroll
      for (int nf = 0; nf < 4; ++nf)
        acc[mm][nf] = __builtin_amdgcn_mfma_f32_16x16x32_bf16(af[mm], bf[nf], acc[mm][nf], 0, 0, 0);
    __builtin_amdgcn_s_setprio(0);
    __builtin_amdgcn_s_barrier();

    // ---------------- P4: k1, m4-7 x n0-3; stage B0(t+2) into CURRENT buf (freed by P3 bar);
    //                  counted vmcnt at tile boundary
#pragma unroll
    for (int mm = 0; mm < 4; ++mm) af[mm] = *(const short8*)&pA[swz((mm + 4) * 16 + l15, 1)];
    if (s2) SH_B(buf, 0, t + 2);
    BARMFMA_HEAD
#pragma unroll
    for (int mm = 0; mm < 4; ++mm)
#pragma unroll
      for (int nf = 0; nf < 4; ++nf)
        acc[mm + 4][nf] = __builtin_amdgcn_mfma_f32_16x16x32_bf16(af[mm], bf[nf], acc[mm + 4][nf], 0, 0, 0);
    __builtin_amdgcn_s_setprio(0);
    if (t < NT - 2) {
      asm volatile("s_waitcnt vmcnt(2)" ::: "memory");  // tile t+1 landed; B0(t+2) in flight
    } else if (t == NT - 2) {
      asm volatile("s_waitcnt vmcnt(0)" ::: "memory");  // tail: tile 11 landed
    }
    __builtin_amdgcn_s_barrier();
  }

#undef SH_A
#undef SH_B
#undef BARMFMA_HEAD

  // epilogue: per-row max over the 256-col tile.
  // C frag layout: col = l15 (+n*16), row = quad*4 + rr (+m*16, +wm*128)
  // s_max overlays As[0][0]: buf0 last read by tile 10 (drained by its own barriers);
  // last stages into As buf0 (A0/A1(11) at P2/P3(10)) landed by vmcnt(0)@P4(10).
  float* s_max = reinterpret_cast<float*>(&As[0][0][0]);
#pragma unroll
  for (int m = 0; m < 8; ++m) {
#pragma unroll
    for (int rr = 0; rr < 4; ++rr) {
      float best = fmaxf(fmaxf(acc[m][0][rr], acc[m][1][rr]),
                         fmaxf(acc[m][2][rr], acc[m][3][rr]));
      best = fmaxf(best, __shfl_xor(best, 1));
      best = fmaxf(best, __shfl_xor(best, 2));
      best = fmaxf(best, __shfl_xor(best, 4));
      best = fmaxf(best, __shfl_xor(best, 8));
      if (l15 == 0)
        s_max[wn * 256 + wm * 128 + m * 16 + quad * 4 + rr] = best;  // unique writer per entry
    }
  }
  __syncthreads();
  if (tid < 256) {
    float mx = fmaxf(fmaxf(s_max[tid], s_max[256 + tid]),
                     fmaxf(s_max[512 + tid], s_max[768 + tid]));
    atomicMax(&part[row_base + tid], enc_f32(mx));
  }
}

// ---------------------------------------------------------------- K5: decode + loss
// single block, 1024 threads; output fp32 scalar
__global__ void finish_kernel(const u32* __restrict__ part, float* __restrict__ out) {
  float v = 0.f;
  for (int i = threadIdx.x; i < NPIX; i += 1024) {
    v += 1.0f - dec_f32(part[i]);
  }
#pragma unroll
  for (int off = 32; off > 0; off >>= 1) v += __shfl_down(v, off);
  __shared__ float red[16];
  int w = threadIdx.x >> 6;
  if ((threadIdx.x & 63) == 0) red[w] = v;
  __syncthreads();
  if (threadIdx.x == 0) {
    float s = 0.f;
#pragma unroll
    for (int k = 0; k < 16; ++k) s += red[k];
    out[0] = s * (1.0f / (float)NPIX);
  }
}

// ---------------------------------------------------------------- launcher
extern "C" void kernel_launch(void* const* d_in, const int* in_sizes, int n_in,
                              void* d_out, int out_size, void* d_ws, size_t ws_size,
                              hipStream_t stream) {
  const float* x = (const float*)d_in[0];
  const float* s = (const float*)d_in[1];
  char* ws = (char*)d_ws;
  // layout (bytes):
  float* pa   = (float*)(ws + 0);         //   401408
  float* pb   = (float*)(ws + 401408);    //   401408
  float* ra   = (float*)(ws + 802816);    //    50176
  float* rb   = (float*)(ws + 852992);    //    50176
  u32*   part = (u32*)  (ws + 903168);    //    50176 (encoded row maxima)
  u16*   Ar   = (u16*)  (ws + 953344);    // 19267584
  u16*   Br   = (u16*)  (ws + 20220928);  // 19267584  -> total 39488512 B

  colsumsq_kernel<<<dim3(49, 8), 256, 0, stream>>>(x, s, pa, pb);
  rnorm_kernel<<<49, 256, 0, stream>>>(pa, pb, ra, rb, part);
  transpose_kernel<<<dim3(392, 24, 2), 256, 0, stream>>>(x, s, ra, rb, Ar, Br);
  gemm_max_kernel<<<dim3(8, 301), 512, 0, stream>>>(Ar, Br, part);
  finish_kernel<<<1, 1024, 0, stream>>>(part, (float*)d_out);
}

// Round 11
// 370.588 us; speedup vs baseline: 4.9198x; 1.1070x over previous
//
#include <hip/hip_runtime.h>
#include <hip/hip_bf16.h>

typedef unsigned short u16;
typedef unsigned int u32;
typedef __attribute__((ext_vector_type(8))) short short8;
typedef __attribute__((ext_vector_type(4))) float floatx4;

#define NPIX 12544   // 112*112 = 49 * 256
#define KDIM 768     // channels = 24 * 32
#define EPSF 1e-8f
#define NCH 24       // K chunks of 32
#define NTILE 49     // 12544 / 256

// ---------------------------------------------------------------- async G->LDS
__device__ __forceinline__ void gload_lds16(const void* g, void* l) {
  __builtin_amdgcn_global_load_lds(
      (const __attribute__((address_space(1))) void*)g,
      (__attribute__((address_space(3))) void*)l, 16, 0, 0);
}

// sortable-uint encoding of float (monotone): max over enc == max over float
__device__ __forceinline__ u32 enc_f32(float f) {
  u32 u = __float_as_uint(f);
  return (u & 0x80000000u) ? ~u : (u | 0x80000000u);
}
__device__ __forceinline__ float dec_f32(u32 e) {
  u32 u = (e & 0x80000000u) ? (e & 0x7FFFFFFFu) : ~e;
  return __uint_as_float(u);
}

// ---------------------------------------------------------------- K0: zero the sumsq accumulators
// grid 49, block 256
__global__ void zero_kernel(float* __restrict__ pa, float* __restrict__ pb) {
  int i = blockIdx.x * 256 + threadIdx.x;
  pa[i] = 0.f;
  pb[i] = 0.f;
}

// ---------------------------------------------------------------- K1: transpose + bf16 cast + FUSED sumsq
// (C,N) f32 -> (N,C) bf16, raw values (normalization moved to GEMM epilogue / finish:
// argmax_j (a_n.b_n) == argmax_j (a.b)*rb[j], cossim = max_j((a.b)*rb[j]) * ra[i], ra,rb>0).
// Fusing the column sum-of-squares here deletes the separate colsumsq kernel's 77MB HBM pass.
// grid (392, 24, 2), block 256 (=32x8); per (row gi, 32-c block): 32-lane shfl reduce + 1 atomicAdd.
__global__ void transpose_kernel(const float* __restrict__ a, const float* __restrict__ b,
                                 u16* __restrict__ Ar, u16* __restrict__ Br,
                                 float* __restrict__ pa, float* __restrict__ pb) {
  const float* src = blockIdx.z ? b : a;
  u16* dst         = blockIdx.z ? Br : Ar;
  float* psum      = blockIdx.z ? pb : pa;
  __shared__ float tile[32][33];
  int i0 = blockIdx.x * 32;
  int c0 = blockIdx.y * 32;
  int tx = threadIdx.x & 31;
  int ty = threadIdx.x >> 5;  // 0..7
#pragma unroll
  for (int d = 0; d < 4; ++d) {
    int c = c0 + ty + d * 8;
    tile[ty + d * 8][tx] = src[(size_t)c * NPIX + i0 + tx];
  }
  __syncthreads();
#pragma unroll
  for (int d = 0; d < 4; ++d) {
    int il = ty + d * 8;
    int gi = i0 + il;
    float v = tile[tx][il];
    __hip_bfloat16 h = __float2bfloat16(v);
    dst[(size_t)gi * KDIM + c0 + tx] = *reinterpret_cast<u16*>(&h);
    // 32-c partial sum of squares for row gi (lanes of each 32-half share gi)
    float sq = v * v;
    sq += __shfl_xor(sq, 1);
    sq += __shfl_xor(sq, 2);
    sq += __shfl_xor(sq, 4);
    sq += __shfl_xor(sq, 8);
    sq += __shfl_xor(sq, 16);
    if (tx == 0) atomicAdd(&psum[gi], sq);
  }
}

// ---------------------------------------------------------------- K2: 1/(sqrt(sum+eps)+eps) + zero the atomic-max buffer
// grid 49, block 256
__global__ void rnorm_kernel(const float* __restrict__ pa, const float* __restrict__ pb,
                             float* __restrict__ ra, float* __restrict__ rb,
                             u32* __restrict__ part) {
  int i = blockIdx.x * 256 + threadIdx.x;
  ra[i] = 1.f / (sqrtf(pa[i] + EPSF) + EPSF);
  rb[i] = 1.f / (sqrtf(pb[i] + EPSF) + EPSF);
  part[i] = 0u;  // encoded floor (< enc of any finite float)
}

// ---------------------------------------------------------------- K4: 256x256 tile, 8 waves,
// counted-vmcnt 4-slot ring (r7 structure, best measured: 274.6us / 39% MfmaUtil), with
// round-11 changes: (a) vmcnt depth 4 -> 8 (2 chunks in flight, m201-style; tail 8/4/0),
// (b) epilogue scales acc by rb[col] before the row-max (raw-bf16 GEMM; see K1 comment).
// Structure unchanged otherwise: K split into 24 chunks of BK=32; LDS = 4 ring slots per
// matrix (slot = chunk&3, 16KB each; 128 KiB total, 1 block/CU). Chunk c body: reads af2
// (slot c) || MFMA phi1 (pre-read frags) with SGB interleave ladder; vmcnt(8)+barrier
// (slot c+1 landed; c+2,c+3 stay in flight); stage c+3 -> slot (c-1)&3 (readers done at the
// barrier); read next-chunk frags || MFMA phi2 with SGB ladder.
// Swizzle (r5-proven, 0 conflicts): LDS(row r, 16B-slot s) holds k-group (s-(r>>1))&3;
// global source pre-swizzled, LDS dest linear (both-sides-or-neither, rule #21).
// Dispatch (r7-proven balance): grid (8,301): XCD k owns cols {k,k+8,...,k+40}, rt slow
// chip-synced; col-48 remainder round-robins rows across XCDs. 300/301 blocks per XCD.
__global__ __launch_bounds__(512, 2) void gemm_max_kernel(const u16* __restrict__ Ar,
                                                          const u16* __restrict__ Br,
                                                          const float* __restrict__ rb,
                                                          u32* __restrict__ part) {
  const int xcd = blockIdx.x;   // linear%8 round-robins XCDs
  const int idx = blockIdx.y;   // 0..300 sequence within XCD
  int ct, rt;
  if (idx < 294) {
    ct = (idx % 6) * 8 + xcd;   // cols {xcd, 8+xcd, ..., 40+xcd} -> B pinned per XCD
    rt = idx / 6;               // rows advance slowly, chip-synchronized
  } else {
    int j = (idx - 294) * 8 + xcd;  // col 48 remainder: rows round-robin XCDs
    if (j >= NTILE) return;         // 7 dead blocks (xcd>0 at idx==300)
    ct = 48; rt = j;
  }
  const int row_base = rt * 256;
  const int col_base = ct * 256;

  __shared__ alignas(16) u16 As[4 * 8192];  // 4 ring slots: [256 rows][4 slots][8 elems]
  __shared__ alignas(16) u16 Bs[4 * 8192];

  const int tid = threadIdx.x;
  const int lane = tid & 63;
  const int wid = tid >> 6;   // 0..7
  const int wm = wid >> 2;    // A half (0..1)
  const int wn = wid & 3;     // B quarter (0..3)
  const int l15 = lane & 15;
  const int quad = lane >> 4;

  // staging: thread covers rows (tid>>2) and (tid>>2)+128, 16B slot tid&3.
  const int srow = tid >> 2;                       // 0..127
  const int clog = ((tid & 3) - (srow >> 1)) & 3;  // logical 8-elem k-group (pre-swizzled)
  const u16* gAt = Ar + (size_t)(row_base + srow) * KDIM + clog * 8;
  const u16* gBt = Br + (size_t)(col_base + srow) * KDIM + clog * 8;
  u16* lA = &As[tid * 8];
  u16* lB = &Bs[tid * 8];

#define STAGE4(T)                                                              \
  do {                                                                         \
    gload_lds16(gAt + (T) * 32,              lA + (((T) & 3) << 13));          \
    gload_lds16(gAt + (T) * 32 + 128 * KDIM, lA + (((T) & 3) << 13) + 4096);   \
    gload_lds16(gBt + (T) * 32,              lB + (((T) & 3) << 13));          \
    gload_lds16(gBt + (T) * 32 + 128 * KDIM, lB + (((T) & 3) << 13) + 4096);   \
  } while (0)

  // frag element offsets within a slot: row R, k-quad quad -> R*32 + (((R>>1)+quad)&3)*8
  int aoff[8], boff[4];
#pragma unroll
  for (int mm = 0; mm < 8; ++mm) {
    int R = wm * 128 + mm * 16 + l15;
    aoff[mm] = R * 32 + ((((R >> 1) + quad) & 3) << 3);
  }
#pragma unroll
  for (int nf = 0; nf < 4; ++nf) {
    int Cc = wn * 64 + nf * 16 + l15;
    boff[nf] = Cc * 32 + ((((Cc >> 1) + quad) & 3) << 3);
  }

  floatx4 acc[8][4];
#pragma unroll
  for (int m = 0; m < 8; ++m)
#pragma unroll
    for (int n = 0; n < 4; ++n) acc[m][n] = (floatx4){0.f, 0.f, 0.f, 0.f};

  // prologue: stage chunks 0,1,2; wait chunk 0 landed (1,2 stay in flight); prime frags
  STAGE4(0); STAGE4(1); STAGE4(2);
  asm volatile("s_waitcnt vmcnt(8)" ::: "memory");
  __builtin_amdgcn_s_barrier();
  __builtin_amdgcn_sched_barrier(0);

  short8 afc[4], bfc[4];
#pragma unroll
  for (int mm = 0; mm < 4; ++mm) afc[mm] = *(const short8*)&As[aoff[mm]];
#pragma unroll
  for (int nf = 0; nf < 4; ++nf) bfc[nf] = *(const short8*)&Bs[boff[nf]];

#define CHUNK(C, DOSTG, VMSTR, DOWAIT, DONEXT)                                                \
  do {                                                                                        \
    const u16* pAs = &As[((C) & 3) << 13];                                                    \
    const u16* pBs = &Bs[((C) & 3) << 13];                                                    \
    const u16* pAn = &As[(((C) + 1) & 3) << 13];                                              \
    const u16* pBn = &Bs[(((C) + 1) & 3) << 13];                                              \
    (void)pBs;                                                                                \
    short8 af2[4], afn[4], bfn[4];                                                            \
    /* R1: af2 reads (slot C) || phi1 MFMA (afc,bfc ready in regs) */                         \
    _Pragma("unroll") for (int mm = 0; mm < 4; ++mm)                                          \
        af2[mm] = *(const short8*)&pAs[aoff[mm + 4]];                                         \
    _Pragma("unroll") for (int mm = 0; mm < 4; ++mm)                                          \
      _Pragma("unroll") for (int nf = 0; nf < 4; ++nf)                                        \
          acc[mm][nf] = __builtin_amdgcn_mfma_f32_16x16x32_bf16(afc[mm], bfc[nf],             \
                                                                acc[mm][nf], 0, 0, 0);        \
    _Pragma("unroll") for (int g = 0; g < 4; ++g) {                                           \
      __builtin_amdgcn_sched_group_barrier(0x100, 1, 0); /* 1 ds_read      */                 \
      __builtin_amdgcn_sched_group_barrier(0x008, 4, 0); /* 4 mfma         */                 \
    }                                                                                         \
    if (DOWAIT) {                                                                             \
      asm volatile("s_waitcnt " VMSTR ::: "memory");                                          \
      __builtin_amdgcn_s_barrier();           /* slot C+1 landed; C-1 reads all done */       \
      __builtin_amdgcn_sched_barrier(0);                                                      \
    }                                                                                         \
    if (DOSTG) STAGE4((C) + 3);                                                               \
    /* R2: next-chunk frag reads (slot C+1) || phi2 MFMA (af2 from R1, lgkm-covered) */       \
    if (DONEXT) {                                                                             \
      _Pragma("unroll") for (int mm = 0; mm < 4; ++mm)                                        \
          afn[mm] = *(const short8*)&pAn[aoff[mm]];                                           \
      _Pragma("unroll") for (int nf = 0; nf < 4; ++nf)                                        \
          bfn[nf] = *(const short8*)&pBn[boff[nf]];                                           \
    }                                                                                         \
    _Pragma("unroll") for (int mm = 0; mm < 4; ++mm)                                          \
      _Pragma("unroll") for (int nf = 0; nf < 4; ++nf)                                        \
          acc[mm + 4][nf] = __builtin_amdgcn_mfma_f32_16x16x32_bf16(af2[mm], bfc[nf],         \
                                                                    acc[mm + 4][nf], 0, 0, 0);\
    if (DONEXT) {                                                                             \
      _Pragma("unroll") for (int g = 0; g < 8; ++g) {                                         \
        __builtin_amdgcn_sched_group_barrier(0x100, 1, 0); /* 1 ds_read    */                 \
        __builtin_amdgcn_sched_group_barrier(0x008, 2, 0); /* 2 mfma       */                 \
      }                                                                                       \
      _Pragma("unroll") for (int mm = 0; mm < 4; ++mm) afc[mm] = afn[mm];                     \
      _Pragma("unroll") for (int nf = 0; nf < 4; ++nf) bfc[nf] = bfn[nf];                     \
    }                                                                                         \
  } while (0)

  // vmcnt ledger: at chunk C's wait, outstanding stages are for C+1 (issued C-2), C+2
  // (issued C-1), C+3 (issued C). vmcnt(8) -> C+1's 4 landed, 8 (C+2,C+3) in flight.
  // Tail: last stage issued at chunk 20 (for c23). c21: outstanding c22+c23 -> vmcnt(4)
  // (c22 landed). c22: outstanding c23 -> vmcnt(0). c23: none.
  CHUNK(0,  1, "vmcnt(8)", 1, 1);  CHUNK(1,  1, "vmcnt(8)", 1, 1);
  CHUNK(2,  1, "vmcnt(8)", 1, 1);  CHUNK(3,  1, "vmcnt(8)", 1, 1);
  CHUNK(4,  1, "vmcnt(8)", 1, 1);  CHUNK(5,  1, "vmcnt(8)", 1, 1);
  CHUNK(6,  1, "vmcnt(8)", 1, 1);  CHUNK(7,  1, "vmcnt(8)", 1, 1);
  CHUNK(8,  1, "vmcnt(8)", 1, 1);  CHUNK(9,  1, "vmcnt(8)", 1, 1);
  CHUNK(10, 1, "vmcnt(8)", 1, 1);  CHUNK(11, 1, "vmcnt(8)", 1, 1);
  CHUNK(12, 1, "vmcnt(8)", 1, 1);  CHUNK(13, 1, "vmcnt(8)", 1, 1);
  CHUNK(14, 1, "vmcnt(8)", 1, 1);  CHUNK(15, 1, "vmcnt(8)", 1, 1);
  CHUNK(16, 1, "vmcnt(8)", 1, 1);  CHUNK(17, 1, "vmcnt(8)", 1, 1);
  CHUNK(18, 1, "vmcnt(8)", 1, 1);  CHUNK(19, 1, "vmcnt(8)", 1, 1);
  CHUNK(20, 1, "vmcnt(8)", 1, 1);
  CHUNK(21, 0, "vmcnt(4)", 1, 1);
  CHUNK(22, 0, "vmcnt(0)", 1, 1);
  CHUNK(23, 0, "vmcnt(0)", 0, 0);

#undef CHUNK
#undef STAGE4

  // epilogue: per-row max over the 256-col tile of acc * rb[col] (raw-dot normalization).
  // C frag layout: col = l15 (+nf*16), row = quad*4 + rr (+m*16, +wm*128)
  float rbv[4];
#pragma unroll
  for (int nf = 0; nf < 4; ++nf) rbv[nf] = rb[col_base + wn * 64 + nf * 16 + l15];

  float* s_max = reinterpret_cast<float*>(&As[0]);  // [4][256], overlays As (done with LDS)
#pragma unroll
  for (int m = 0; m < 8; ++m) {
#pragma unroll
    for (int rr = 0; rr < 4; ++rr) {
      float best = fmaxf(fmaxf(acc[m][0][rr] * rbv[0], acc[m][1][rr] * rbv[1]),
                         fmaxf(acc[m][2][rr] * rbv[2], acc[m][3][rr] * rbv[3]));
      best = fmaxf(best, __shfl_xor(best, 1));
      best = fmaxf(best, __shfl_xor(best, 2));
      best = fmaxf(best, __shfl_xor(best, 4));
      best = fmaxf(best, __shfl_xor(best, 8));
      if (l15 == 0)
        s_max[wn * 256 + wm * 128 + m * 16 + quad * 4 + rr] = best;  // unique writer per entry
    }
  }
  __syncthreads();
  if (tid < 256) {
    float mx = fmaxf(fmaxf(s_max[tid], s_max[256 + tid]),
                     fmaxf(s_max[512 + tid], s_max[768 + tid]));
    atomicMax(&part[row_base + tid], enc_f32(mx));
  }
}

// ---------------------------------------------------------------- K5: decode + apply ra + loss
// single block, 1024 threads; output fp32 scalar. part holds max_j (a.b)*rb[j]; x ra[i] here.
__global__ void finish_kernel(const u32* __restrict__ part, const float* __restrict__ ra,
                              float* __restrict__ out) {
  float v = 0.f;
  for (int i = threadIdx.x; i < NPIX; i += 1024) {
    v += 1.0f - dec_f32(part[i]) * ra[i];
  }
#pragma unroll
  for (int off = 32; off > 0; off >>= 1) v += __shfl_down(v, off);
  __shared__ float red[16];
  int w = threadIdx.x >> 6;
  if ((threadIdx.x & 63) == 0) red[w] = v;
  __syncthreads();
  if (threadIdx.x == 0) {
    float s = 0.f;
#pragma unroll
    for (int k = 0; k < 16; ++k) s += red[k];
    out[0] = s * (1.0f / (float)NPIX);
  }
}

// ---------------------------------------------------------------- launcher
extern "C" void kernel_launch(void* const* d_in, const int* in_sizes, int n_in,
                              void* d_out, int out_size, void* d_ws, size_t ws_size,
                              hipStream_t stream) {
  const float* x = (const float*)d_in[0];
  const float* s = (const float*)d_in[1];
  char* ws = (char*)d_ws;
  // layout (bytes):
  float* pa   = (float*)(ws + 0);         //    50176 (sumsq accum, region oversized)
  float* pb   = (float*)(ws + 401408);    //    50176
  float* ra   = (float*)(ws + 802816);    //    50176
  float* rb   = (float*)(ws + 852992);    //    50176
  u32*   part = (u32*)  (ws + 903168);    //    50176 (encoded row maxima)
  u16*   Ar   = (u16*)  (ws + 953344);    // 19267584
  u16*   Br   = (u16*)  (ws + 20220928);  // 19267584  -> total 39488512 B

  zero_kernel<<<49, 256, 0, stream>>>(pa, pb);
  transpose_kernel<<<dim3(392, 24, 2), 256, 0, stream>>>(x, s, Ar, Br, pa, pb);
  rnorm_kernel<<<49, 256, 0, stream>>>(pa, pb, ra, rb, part);
  gemm_max_kernel<<<dim3(8, 301), 512, 0, stream>>>(Ar, Br, rb, part);
  finish_kernel<<<1, 1024, 0, stream>>>(part, ra, (float*)d_out);
}